// Round 13
// baseline (120.392 us; speedup 1.0000x reference)
//
#include <hip/hip_runtime.h>
#include <math.h>

typedef __bf16 bf16x8 __attribute__((ext_vector_type(8)));
typedef float f32x4 __attribute__((ext_vector_type(4)));

#define MFMA16(a, b, c) __builtin_amdgcn_mfma_f32_16x16x32_bf16(a, b, c, 0, 0, 0)

static constexpr int M_TOT = 8192;   // B*S
static constexpr int DIN = 4096;
static constexpr int DOUT = 4096;
static constexpr int RNK = 64;

__device__ inline unsigned short f2bf(float f) {
    union { float f; unsigned u; } v; v.f = f;
    unsigned r = v.u + 0x7FFFu + ((v.u >> 16) & 1u);   // round-to-nearest-even
    return (unsigned short)(r >> 16);
}

// ---------------------------------------------------------------------------
// Fragment-major layout: block (tile,slice) holds the 64 lanes' bf16x8
// contiguously; every wave fragment load = one coalesced 1 KB instruction.
// ---------------------------------------------------------------------------
__global__ __launch_bounds__(256) void k_prep(const float* __restrict__ A,
                                              const float* __restrict__ B,
                                              unsigned short* __restrict__ Afrag,
                                              unsigned short* __restrict__ Atfrag,
                                              unsigned short* __restrict__ Bfrag) {
    int i = blockIdx.x * 256 + threadIdx.x;          // 0 .. 262143
    unsigned short ab = f2bf(A[i]);
    int n = i >> 12, k = i & 4095;                   // A[n][k]
    Afrag[(((k >> 5) << 2) + (n >> 4)) * 512 +
          ((((k >> 3) & 3) << 4) + (n & 15)) * 8 + (k & 7)] = ab;
    Atfrag[(((k >> 4) << 1) + (n >> 5)) * 512 +
           ((((n >> 3) & 3) << 4) + (k & 15)) * 8 + (n & 7)] = ab;
    unsigned short bb = f2bf(B[i]);
    int o = i >> 6, r = i & 63;
    Bfrag[(((o >> 4) << 1) + (r >> 5)) * 512 +
          ((((r >> 3) & 3) << 4) + (o & 15)) * 8 + (r & 7)] = bb;
}

// ---------------------------------------------------------------------------
// kAB: barrier-free streaming roles (x and bw are single-use: NO LDS staging,
// each lane loads its own MFMA fragment bytes directly; the k/i loop has zero
// barriers so the compiler software-pipelines loads with counted vmcnt, and
// 4096 small equal blocks give deep block-level TLP).
//   even blocks (2048): k1 role — partial xa = x @ A^T over 16m x 1024k
//   odd  blocks (2048): k2 role — partial sq-norm over 16o x 512i
// ---------------------------------------------------------------------------
__global__ __launch_bounds__(256) void kAB(const float* __restrict__ x,
                                           const unsigned short* __restrict__ Afrag,
                                           float* __restrict__ pxa,
                                           const float* __restrict__ bw,
                                           const unsigned short* __restrict__ Bfrag,
                                           const unsigned short* __restrict__ Atfrag,
                                           float* __restrict__ pn) {
    __shared__ __align__(16) float red[4][1024];     // k1 reduce; k2 uses 64 floats
    int tid = threadIdx.x;
    int wid = tid >> 6, lane = tid & 63;
    int row = lane & 15, kq = lane >> 4;
    int lane8 = lane * 8;
    int sub = blockIdx.x >> 1;

    if ((blockIdx.x & 1) == 0) {
        // ---------------- role 1: xa GEMM, direct fragment loads ------------
        int mt = sub & 511, kpart = sub >> 9;        // 512 m-tiles x 4 k-parts
        int m0 = mt * 16;
        const float* xrow = x + (size_t)(m0 + row) * DIN;

        f32x4 acc0 = {0.f, 0.f, 0.f, 0.f};
        f32x4 acc1 = acc0, acc2 = acc0, acc3 = acc0;

        #pragma unroll
        for (int s = 0; s < 8; ++s) {                // wave's 256k as 8 steps of 32
            int k = kpart * 1024 + wid * 256 + s * 32 + kq * 8;
            f32x4 xlo = *(const f32x4*)(xrow + k);
            f32x4 xhi = *(const f32x4*)(xrow + k + 4);
            int ks = (kpart * 1024 + wid * 256 + s * 32) >> 5;
            const unsigned short* ap = Afrag + (size_t)ks * 2048 + lane8;
            bf16x8 af;
            #pragma unroll
            for (int j = 0; j < 4; ++j) { af[j] = (__bf16)xlo[j]; af[j + 4] = (__bf16)xhi[j]; }
            acc0 = MFMA16(af, *(const bf16x8*)(ap), acc0);
            acc1 = MFMA16(af, *(const bf16x8*)(ap + 512), acc1);
            acc2 = MFMA16(af, *(const bf16x8*)(ap + 1024), acc2);
            acc3 = MFMA16(af, *(const bf16x8*)(ap + 1536), acc3);
        }

        int mb = kq * 4;                              // C: row=(lane>>4)*4+reg
        #pragma unroll
        for (int rg = 0; rg < 4; ++rg) {
            red[wid][(mb + rg) * 64 + row]      = acc0[rg];
            red[wid][(mb + rg) * 64 + 16 + row] = acc1[rg];
            red[wid][(mb + rg) * 64 + 32 + row] = acc2[rg];
            red[wid][(mb + rg) * 64 + 48 + row] = acc3[rg];
        }
        __syncthreads();                              // the ONLY barrier
        #pragma unroll
        for (int e = tid; e < 1024; e += 256) {
            float s = red[0][e] + red[1][e] + red[2][e] + red[3][e];
            pxa[(size_t)kpart * M_TOT * RNK + (size_t)(m0 + (e >> 6)) * RNK + (e & 63)] = s;
        }
    } else {
        // ---------------- role 2: DoRA norm partials, direct loads ----------
        int ot = sub & 255, ipart = sub >> 8;        // 256 o-tiles x 8 i-parts
        int o0 = ot * 16;
        const float* bwrow = bw + (size_t)(o0 + row) * DIN;

        bf16x8 b0 = *(const bf16x8*)(Bfrag + (size_t)(ot * 2) * 512 + lane8);
        bf16x8 b1 = *(const bf16x8*)(Bfrag + (size_t)(ot * 2 + 1) * 512 + lane8);

        f32x4 nacc = {0.f, 0.f, 0.f, 0.f};
        #pragma unroll
        for (int g = 0; g < 8; ++g) {                // wave's 128i as 8 steps of 16
            int i0 = ipart * 512 + wid * 128 + g * 16;
            int it = i0 >> 4;
            const unsigned short* atp = Atfrag + (size_t)it * 1024 + lane8;
            bf16x8 a0 = *(const bf16x8*)(atp);
            bf16x8 a1 = *(const bf16x8*)(atp + 512);
            f32x4 d = {0.f, 0.f, 0.f, 0.f};
            d = MFMA16(a0, b0, d);                   // delta[o=o0+row][i=i0+kq*4+rg]
            d = MFMA16(a1, b1, d);
            f32x4 wv = *(const f32x4*)(bwrow + i0 + kq * 4);
            #pragma unroll
            for (int rg = 0; rg < 4; ++rg) {
                float w = wv[rg] + 2.0f * d[rg];
                nacc[rg] += w * w;
            }
        }
        float ns = nacc[0] + nacc[1] + nacc[2] + nacc[3];
        ns += __shfl_xor(ns, 16, 64);
        ns += __shfl_xor(ns, 32, 64);
        if (kq == 0) red[0][wid * 16 + row] = ns;
        __syncthreads();
        if (tid < 16)
            pn[ipart * DOUT + o0 + tid] = red[0][tid] + red[0][16 + tid] +
                                          red[0][32 + tid] + red[0][48 + tid];
    }
}

// ---------------------------------------------------------------------------
// kfin: blocks 0..511: xa frag-major bf16 <- sum of 4 pxa planes;
//       blocks 512..527: mscale[o] = mag[o]/(sqrt(sum of 8 pn planes)+eps)
// ---------------------------------------------------------------------------
__global__ __launch_bounds__(256) void kfin(const float* __restrict__ pxa,
                                            unsigned short* __restrict__ xafrag,
                                            const float* __restrict__ pn,
                                            const float* __restrict__ mag,
                                            float* __restrict__ mscale) {
    int tid = threadIdx.x;
    if (blockIdx.x < 512) {
        int mt = blockIdx.x;
        int e0 = tid * 4;
        size_t o = (size_t)(mt * 16 + (e0 >> 6)) * RNK + (e0 & 63);
        f32x4 s0 = *(const f32x4*)(pxa + o);
        f32x4 s1 = *(const f32x4*)(pxa + (size_t)M_TOT * RNK + o);
        f32x4 s2 = *(const f32x4*)(pxa + 2 * (size_t)M_TOT * RNK + o);
        f32x4 s3 = *(const f32x4*)(pxa + 3 * (size_t)M_TOT * RNK + o);
        int ml = e0 >> 6, r0 = e0 & 63;
        ushort4 h;
        h.x = f2bf(s0[0] + s1[0] + s2[0] + s3[0]);
        h.y = f2bf(s0[1] + s1[1] + s2[1] + s3[1]);
        h.z = f2bf(s0[2] + s1[2] + s2[2] + s3[2]);
        h.w = f2bf(s0[3] + s1[3] + s2[3] + s3[3]);
        *(ushort4*)&xafrag[((size_t)(mt * 2 + (r0 >> 5))) * 512 +
                           ((((r0 >> 3) & 3) << 4) + ml) * 8 + (r0 & 7)] = h;
    } else {
        int o = (int)(blockIdx.x - 512) * 256 + tid;
        float n2 = 0.f;
        #pragma unroll
        for (int p = 0; p < 8; ++p) n2 += pn[p * DOUT + o];
        mscale[o] = mag[o] / (sqrtf(n2) + 1e-8f);
    }
}

// ---------------------------------------------------------------------------
// kB: out = (base_output + 2 * xa @ lora_B^T) * mscale   (proven r7/r9 form)
// ---------------------------------------------------------------------------
__global__ __launch_bounds__(256) void kB(const float* __restrict__ base,
                                          const unsigned short* __restrict__ xafrag,
                                          const unsigned short* __restrict__ Bfrag,
                                          const float* __restrict__ mscale,
                                          float* __restrict__ out) {
    __shared__ float dls[32][260];                   // 33.3 KB, +4 pad
    int tid = threadIdx.x;
    int wid = tid >> 6, lane = tid & 63;
    int row = lane & 15, kq = lane >> 4;
    int m0 = blockIdx.x * 32;
    int n0 = blockIdx.y * 256;
    int col = n0 + lane * 4;
    int lane8 = lane * 8;

    f32x4 bpre[2][4];
    #pragma unroll
    for (int h = 0; h < 2; ++h)
        #pragma unroll
        for (int r = 0; r < 4; ++r)
            bpre[h][r] = __builtin_nontemporal_load(
                (const f32x4*)(base + (size_t)(m0 + h * 16 + wid * 4 + r) * DOUT + col));
    f32x4 msv = *(const f32x4*)(mscale + col);

    bf16x8 xb0[2], xb1[2];
    #pragma unroll
    for (int h = 0; h < 2; ++h) {
        size_t mt = (size_t)(blockIdx.x * 2 + h);
        xb0[h] = *(const bf16x8*)(xafrag + (mt * 2) * 512 + lane8);
        xb1[h] = *(const bf16x8*)(xafrag + (mt * 2 + 1) * 512 + lane8);
    }

    #pragma unroll
    for (int nt = 0; nt < 4; ++nt) {
        size_t ntg = (size_t)((n0 + wid * 64 + nt * 16) >> 4);
        bf16x8 a0 = *(const bf16x8*)(Bfrag + (ntg * 2) * 512 + lane8);
        bf16x8 a1 = *(const bf16x8*)(Bfrag + (ntg * 2 + 1) * 512 + lane8);
        #pragma unroll
        for (int h = 0; h < 2; ++h) {
            f32x4 acc = {0.f, 0.f, 0.f, 0.f};
            acc = MFMA16(a0, xb0[h], acc);           // lane: delta[m=row][nloc=kq*4+rg]
            acc = MFMA16(a1, xb1[h], acc);
            *(f32x4*)&dls[h * 16 + row][wid * 64 + nt * 16 + kq * 4] = acc;
        }
    }
    __syncthreads();

    #pragma unroll
    for (int h = 0; h < 2; ++h)
        #pragma unroll
        for (int r = 0; r < 4; ++r) {
            int m = h * 16 + wid * 4 + r;
            f32x4 d = *(const f32x4*)&dls[m][lane * 4];
            size_t gidx = (size_t)(m0 + m) * DOUT + col;
            f32x4 o;
            #pragma unroll
            for (int j = 0; j < 4; ++j) o[j] = (bpre[h][r][j] + 2.0f * d[j]) * msv[j];
            __builtin_nontemporal_store(o, (f32x4*)(out + gidx));
        }
}

extern "C" void kernel_launch(void* const* d_in, const int* in_sizes, int n_in,
                              void* d_out, int out_size, void* d_ws, size_t ws_size,
                              hipStream_t stream) {
    const float* x    = (const float*)d_in[0];   // [2,4096,4096]
    const float* base = (const float*)d_in[1];   // [2,4096,4096]
    const float* bw   = (const float*)d_in[2];   // [4096,4096]
    const float* lA   = (const float*)d_in[3];   // [64,4096]
    const float* lB   = (const float*)d_in[4];   // [4096,64]
    const float* mag  = (const float*)d_in[5];   // [4096]
    float* out = (float*)d_out;

    char* ws = (char*)d_ws;
    unsigned short* Afrag  = (unsigned short*)(ws);                  // 512 KB
    unsigned short* Atfrag = (unsigned short*)(ws + (512u << 10));   // 512 KB
    unsigned short* Bfrag  = (unsigned short*)(ws + (1024u << 10));  // 512 KB
    unsigned short* xafrag = (unsigned short*)(ws + (1536u << 10));  // 1 MB
    float*          pxa    = (float*)(ws + (2560u << 10));           // 8 MB
    float*          pn     = (float*)(ws + (10752u << 10));          // 128 KB
    float*          msc    = (float*)(ws + (10880u << 10));          // 16 KB

    hipLaunchKernelGGL(k_prep, dim3(1024), dim3(256), 0, stream, lA, lB, Afrag, Atfrag, Bfrag);
    hipLaunchKernelGGL(kAB, dim3(4096), dim3(256), 0, stream,
                       x, Afrag, pxa, bw, Bfrag, Atfrag, pn);
    hipLaunchKernelGGL(kfin, dim3(528), dim3(256), 0, stream, pxa, xafrag, pn, mag, msc);
    hipLaunchKernelGGL(kB, dim3(M_TOT / 32, DOUT / 256), dim3(256), 0, stream,
                       base, xafrag, Bfrag, msc, out);
}

// Round 14
// 108.071 us; speedup vs baseline: 1.1140x; 1.1140x over previous
//
#include <hip/hip_runtime.h>
#include <math.h>

typedef __bf16 bf16x8 __attribute__((ext_vector_type(8)));
typedef float f32x4 __attribute__((ext_vector_type(4)));

#define MFMA16(a, b, c) __builtin_amdgcn_mfma_f32_16x16x32_bf16(a, b, c, 0, 0, 0)

static constexpr int M_TOT = 8192;   // B*S
static constexpr int DIN = 4096;
static constexpr int DOUT = 4096;
static constexpr int RNK = 64;

__device__ inline unsigned short f2bf(float f) {
    union { float f; unsigned u; } v; v.f = f;
    unsigned r = v.u + 0x7FFFu + ((v.u >> 16) & 1u);   // round-to-nearest-even
    return (unsigned short)(r >> 16);
}

// async global->LDS, 16 B per lane; LDS dest = wave-uniform base + lane*16
__device__ inline void gload_lds16(const float* g, char* lds_base) {
    __builtin_amdgcn_global_load_lds(
        (const __attribute__((address_space(1))) void*)g,
        (__attribute__((address_space(3))) void*)lds_base, 16, 0, 0);
}

// ---------------------------------------------------------------------------
// Fragment-major layout: block (tile,slice) holds the 64 lanes' bf16x8
// contiguously; every wave fragment load = one coalesced 1 KB instruction.
// ---------------------------------------------------------------------------
__global__ __launch_bounds__(256) void k_prep(const float* __restrict__ A,
                                              const float* __restrict__ B,
                                              unsigned short* __restrict__ Afrag,
                                              unsigned short* __restrict__ Atfrag,
                                              unsigned short* __restrict__ Bfrag) {
    int i = blockIdx.x * 256 + threadIdx.x;          // 0 .. 262143
    unsigned short ab = f2bf(A[i]);
    int n = i >> 12, k = i & 4095;                   // A[n][k]
    Afrag[(((k >> 5) << 2) + (n >> 4)) * 512 +
          ((((k >> 3) & 3) << 4) + (n & 15)) * 8 + (k & 7)] = ab;
    Atfrag[(((k >> 4) << 1) + (n >> 5)) * 512 +
           ((((n >> 3) & 3) << 4) + (k & 15)) * 8 + (n & 7)] = ab;
    unsigned short bb = f2bf(B[i]);
    int o = i >> 6, r = i & 63;
    Bfrag[(((o >> 4) << 1) + (r >> 5)) * 512 +
          ((((r >> 3) & 3) << 4) + (o & 15)) * 8 + (r & 7)] = bb;
}

// ---------------------------------------------------------------------------
// kAB: ONE dispatch; bodies = r11's k1_xa / k2_norm verbatim (the fastest
// measured variants), role-interleaved even/odd so the x and bw HBM streams
// flow concurrently from t=0 and all blocks have equal lifetimes (fixes
// r12's k2-straggler).
//   even blocks (1024): k1 role — 512 m-tiles x 2 K-halves, 8 chunks each
//   odd  blocks (1024): k2 role — 256 o-tiles x 4 i-parts, 4 chunks each
// ---------------------------------------------------------------------------
__global__ __launch_bounds__(256) void kAB(const float* __restrict__ x,
                                           const unsigned short* __restrict__ Afrag,
                                           float* __restrict__ pxa,
                                           const float* __restrict__ bw,
                                           const unsigned short* __restrict__ Bfrag,
                                           const unsigned short* __restrict__ Atfrag,
                                           float* __restrict__ pn) {
    __shared__ __align__(16) char smem[33024];
    char* buf0 = smem;
    char* buf1 = smem + 16384;
    int tid = threadIdx.x;
    int wid = tid >> 6, lane = tid & 63;
    int row = lane & 15, kq = lane >> 4;
    int lane8 = lane * 8;
    int swzr = (row & 7) << 4;
    int sub = blockIdx.x >> 1;

    if ((blockIdx.x & 1) == 0) {
        // ---------------- role 1: xa GEMM (r11 k1_xa body) ----------------
        float (*red)[1024] = (float (*)[1024])smem;  // aliases buf0 after loop
        int mt = sub & 511, kpart = sub >> 9;
        int m0 = mt * 16;
        const float* xbase = x + (size_t)m0 * DIN + kpart * 2048;

        f32x4 acc0 = {0.f, 0.f, 0.f, 0.f};
        f32x4 acc1 = acc0, acc2 = acc0, acc3 = acc0;
        bf16x8 setA[8], setB[8];

        auto STAGE = [&](char* buf, int c) {
            #pragma unroll
            for (int j = 0; j < 4; ++j) {
                int r = wid * 4 + j;
                int srcb = (lane * 16) ^ ((r & 7) << 4);
                const float* g = xbase + (size_t)r * DIN + c * 256 + (srcb >> 2);
                gload_lds16(g, buf + r * 1024);
            }
        };
        auto AFRAG = [&](bf16x8* set, int c) {
            #pragma unroll
            for (int s = 0; s < 2; ++s) {
                int ks = kpart * 64 + c * 8 + wid * 2 + s;
                const unsigned short* ap = Afrag + (size_t)ks * 2048 + lane8;
                set[s * 4 + 0] = *(const bf16x8*)(ap);
                set[s * 4 + 1] = *(const bf16x8*)(ap + 512);
                set[s * 4 + 2] = *(const bf16x8*)(ap + 1024);
                set[s * 4 + 3] = *(const bf16x8*)(ap + 1536);
            }
        };
        auto COMPUTE = [&](const char* buf, const bf16x8* set) {
            #pragma unroll
            for (int s = 0; s < 2; ++s) {
                int kbyte = wid * 256 + s * 128 + kq * 32;
                f32x4 xlo = *(const f32x4*)(buf + row * 1024 + ((kbyte) ^ swzr));
                f32x4 xhi = *(const f32x4*)(buf + row * 1024 + ((kbyte + 16) ^ swzr));
                bf16x8 af;
                #pragma unroll
                for (int j = 0; j < 4; ++j) {
                    af[j] = (__bf16)xlo[j];
                    af[j + 4] = (__bf16)xhi[j];
                }
                acc0 = MFMA16(af, set[s * 4 + 0], acc0);
                acc1 = MFMA16(af, set[s * 4 + 1], acc1);
                acc2 = MFMA16(af, set[s * 4 + 2], acc2);
                acc3 = MFMA16(af, set[s * 4 + 3], acc3);
            }
        };

        STAGE(buf0, 0); AFRAG(setA, 0);
        __syncthreads();
        #pragma unroll
        for (int c = 0; c < 8; c += 2) {
            if (c + 1 < 8) { STAGE(buf1, c + 1); AFRAG(setB, c + 1); }
            COMPUTE(buf0, setA);
            __syncthreads();
            if (c + 2 < 8) { STAGE(buf0, c + 2); AFRAG(setA, c + 2); }
            if (c + 1 < 8) COMPUTE(buf1, setB);
            __syncthreads();
        }

        int mb = kq * 4;                              // C: row=(lane>>4)*4+reg
        #pragma unroll
        for (int rg = 0; rg < 4; ++rg) {
            red[wid][(mb + rg) * 64 + row]      = acc0[rg];
            red[wid][(mb + rg) * 64 + 16 + row] = acc1[rg];
            red[wid][(mb + rg) * 64 + 32 + row] = acc2[rg];
            red[wid][(mb + rg) * 64 + 48 + row] = acc3[rg];
        }
        __syncthreads();
        #pragma unroll
        for (int e = tid; e < 1024; e += 256) {
            float s = red[0][e] + red[1][e] + red[2][e] + red[3][e];
            pxa[(size_t)kpart * M_TOT * RNK + (size_t)(m0 + (e >> 6)) * RNK + (e & 63)] = s;
        }
    } else {
        // ---------------- role 2: DoRA norm partials (r11 k2_norm body) -----
        float (*part)[16] = (float (*)[16])(smem + 32768);
        int ot = sub & 255, ipart = sub >> 8;
        int o0 = ot * 16;
        const float* bwbase = bw + (size_t)o0 * DIN + ipart * 1024;

        bf16x8 b0 = *(const bf16x8*)(Bfrag + (size_t)(ot * 2) * 512 + lane8);
        bf16x8 b1 = *(const bf16x8*)(Bfrag + (size_t)(ot * 2 + 1) * 512 + lane8);

        f32x4 nacc = {0.f, 0.f, 0.f, 0.f};
        bf16x8 setA[8], setB[8];

        auto STAGE = [&](char* buf, int c) {
            #pragma unroll
            for (int j = 0; j < 4; ++j) {
                int r = wid * 4 + j;
                int srcb = (lane * 16) ^ ((r & 7) << 4);
                const float* g = bwbase + (size_t)r * DIN + c * 256 + (srcb >> 2);
                gload_lds16(g, buf + r * 1024);
            }
        };
        auto ATFRAG = [&](bf16x8* set, int c) {
            #pragma unroll
            for (int g = 0; g < 4; ++g) {
                int it = ipart * 64 + c * 16 + wid * 4 + g;
                const unsigned short* atp = Atfrag + (size_t)it * 1024 + lane8;
                set[g * 2]     = *(const bf16x8*)(atp);
                set[g * 2 + 1] = *(const bf16x8*)(atp + 512);
            }
        };
        auto COMPUTE = [&](const char* buf, const bf16x8* set) {
            #pragma unroll
            for (int g = 0; g < 4; ++g) {
                f32x4 d = {0.f, 0.f, 0.f, 0.f};
                d = MFMA16(set[g * 2], b0, d);       // delta[o=o0+row][i=..+kq*4+rg]
                d = MFMA16(set[g * 2 + 1], b1, d);
                int ibyte = wid * 256 + g * 64 + kq * 16;
                f32x4 wv = *(const f32x4*)(buf + row * 1024 + (ibyte ^ swzr));
                #pragma unroll
                for (int rg = 0; rg < 4; ++rg) {
                    float w = wv[rg] + 2.0f * d[rg];
                    nacc[rg] += w * w;
                }
            }
        };

        STAGE(buf0, 0); ATFRAG(setA, 0);
        __syncthreads();
        #pragma unroll
        for (int c = 0; c < 4; c += 2) {
            if (c + 1 < 4) { STAGE(buf1, c + 1); ATFRAG(setB, c + 1); }
            COMPUTE(buf0, setA);
            __syncthreads();
            if (c + 2 < 4) { STAGE(buf0, c + 2); ATFRAG(setA, c + 2); }
            if (c + 1 < 4) COMPUTE(buf1, setB);
            __syncthreads();
        }

        float ns = nacc[0] + nacc[1] + nacc[2] + nacc[3];
        ns += __shfl_xor(ns, 16, 64);
        ns += __shfl_xor(ns, 32, 64);
        if (kq == 0) part[wid][row] = ns;
        __syncthreads();
        if (tid < 16)
            pn[ipart * DOUT + o0 + tid] =
                part[0][tid] + part[1][tid] + part[2][tid] + part[3][tid];
    }
}

// ---------------------------------------------------------------------------
// kfin: blocks 0..511: xa frag-major bf16 <- sum of 2 pxa planes;
//       blocks 512..527: mscale[o] = mag[o]/(sqrt(sum of 4 pn planes)+eps)
// ---------------------------------------------------------------------------
__global__ __launch_bounds__(256) void kfin(const float* __restrict__ pxa,
                                            unsigned short* __restrict__ xafrag,
                                            const float* __restrict__ pn,
                                            const float* __restrict__ mag,
                                            float* __restrict__ mscale) {
    int tid = threadIdx.x;
    if (blockIdx.x < 512) {
        int mt = blockIdx.x;
        int e0 = tid * 4;
        size_t o = (size_t)(mt * 16 + (e0 >> 6)) * RNK + (e0 & 63);
        f32x4 s0 = *(const f32x4*)(pxa + o);
        f32x4 s1 = *(const f32x4*)(pxa + (size_t)M_TOT * RNK + o);
        int ml = e0 >> 6, r0 = e0 & 63;
        ushort4 h;
        h.x = f2bf(s0[0] + s1[0]);
        h.y = f2bf(s0[1] + s1[1]);
        h.z = f2bf(s0[2] + s1[2]);
        h.w = f2bf(s0[3] + s1[3]);
        *(ushort4*)&xafrag[((size_t)(mt * 2 + (r0 >> 5))) * 512 +
                           ((((r0 >> 3) & 3) << 4) + ml) * 8 + (r0 & 7)] = h;
    } else {
        int o = (int)(blockIdx.x - 512) * 256 + tid;
        float n2 = pn[o] + pn[DOUT + o] + pn[2 * DOUT + o] + pn[3 * DOUT + o];
        mscale[o] = mag[o] / (sqrtf(n2) + 1e-8f);
    }
}

// ---------------------------------------------------------------------------
// kB: out = (base_output + 2 * xa @ lora_B^T) * mscale   (proven r7/r9 form)
// ---------------------------------------------------------------------------
__global__ __launch_bounds__(256) void kB(const float* __restrict__ base,
                                          const unsigned short* __restrict__ xafrag,
                                          const unsigned short* __restrict__ Bfrag,
                                          const float* __restrict__ mscale,
                                          float* __restrict__ out) {
    __shared__ float dls[32][260];                   // 33.3 KB, +4 pad
    int tid = threadIdx.x;
    int wid = tid >> 6, lane = tid & 63;
    int row = lane & 15, kq = lane >> 4;
    int m0 = blockIdx.x * 32;
    int n0 = blockIdx.y * 256;
    int col = n0 + lane * 4;
    int lane8 = lane * 8;

    f32x4 bpre[2][4];
    #pragma unroll
    for (int h = 0; h < 2; ++h)
        #pragma unroll
        for (int r = 0; r < 4; ++r)
            bpre[h][r] = __builtin_nontemporal_load(
                (const f32x4*)(base + (size_t)(m0 + h * 16 + wid * 4 + r) * DOUT + col));
    f32x4 msv = *(const f32x4*)(mscale + col);

    bf16x8 xb0[2], xb1[2];
    #pragma unroll
    for (int h = 0; h < 2; ++h) {
        size_t mt = (size_t)(blockIdx.x * 2 + h);
        xb0[h] = *(const bf16x8*)(xafrag + (mt * 2) * 512 + lane8);
        xb1[h] = *(const bf16x8*)(xafrag + (mt * 2 + 1) * 512 + lane8);
    }

    #pragma unroll
    for (int nt = 0; nt < 4; ++nt) {
        size_t ntg = (size_t)((n0 + wid * 64 + nt * 16) >> 4);
        bf16x8 a0 = *(const bf16x8*)(Bfrag + (ntg * 2) * 512 + lane8);
        bf16x8 a1 = *(const bf16x8*)(Bfrag + (ntg * 2 + 1) * 512 + lane8);
        #pragma unroll
        for (int h = 0; h < 2; ++h) {
            f32x4 acc = {0.f, 0.f, 0.f, 0.f};
            acc = MFMA16(a0, xb0[h], acc);           // lane: delta[m=row][nloc=kq*4+rg]
            acc = MFMA16(a1, xb1[h], acc);
            *(f32x4*)&dls[h * 16 + row][wid * 64 + nt * 16 + kq * 4] = acc;
        }
    }
    __syncthreads();

    #pragma unroll
    for (int h = 0; h < 2; ++h)
        #pragma unroll
        for (int r = 0; r < 4; ++r) {
            int m = h * 16 + wid * 4 + r;
            f32x4 d = *(const f32x4*)&dls[m][lane * 4];
            size_t gidx = (size_t)(m0 + m) * DOUT + col;
            f32x4 o;
            #pragma unroll
            for (int j = 0; j < 4; ++j) o[j] = (bpre[h][r][j] + 2.0f * d[j]) * msv[j];
            __builtin_nontemporal_store(o, (f32x4*)(out + gidx));
        }
}

extern "C" void kernel_launch(void* const* d_in, const int* in_sizes, int n_in,
                              void* d_out, int out_size, void* d_ws, size_t ws_size,
                              hipStream_t stream) {
    const float* x    = (const float*)d_in[0];   // [2,4096,4096]
    const float* base = (const float*)d_in[1];   // [2,4096,4096]
    const float* bw   = (const float*)d_in[2];   // [4096,4096]
    const float* lA   = (const float*)d_in[3];   // [64,4096]
    const float* lB   = (const float*)d_in[4];   // [4096,64]
    const float* mag  = (const float*)d_in[5];   // [4096]
    float* out = (float*)d_out;

    char* ws = (char*)d_ws;
    unsigned short* Afrag  = (unsigned short*)(ws);                  // 512 KB
    unsigned short* Atfrag = (unsigned short*)(ws + (512u << 10));   // 512 KB
    unsigned short* Bfrag  = (unsigned short*)(ws + (1024u << 10));  // 512 KB
    unsigned short* xafrag = (unsigned short*)(ws + (1536u << 10));  // 1 MB
    float*          pxa    = (float*)(ws + (2560u << 10));           // 4 MB
    float*          pn     = (float*)(ws + (6656u << 10));           // 64 KB
    float*          msc    = (float*)(ws + (6720u << 10));           // 16 KB

    hipLaunchKernelGGL(k_prep, dim3(1024), dim3(256), 0, stream, lA, lB, Afrag, Atfrag, Bfrag);
    hipLaunchKernelGGL(kAB, dim3(2048), dim3(256), 0, stream,
                       x, Afrag, pxa, bw, Bfrag, Atfrag, pn);
    hipLaunchKernelGGL(kfin, dim3(528), dim3(256), 0, stream, pxa, xafrag, pn, mag, msc);
    hipLaunchKernelGGL(kB, dim3(M_TOT / 32, DOUT / 256), dim3(256), 0, stream,
                       base, xafrag, Bfrag, msc, out);
}

// Round 15
// 107.872 us; speedup vs baseline: 1.1161x; 1.0018x over previous
//
#include <hip/hip_runtime.h>
#include <math.h>

typedef __bf16 bf16x8 __attribute__((ext_vector_type(8)));
typedef float f32x4 __attribute__((ext_vector_type(4)));

#define MFMA16(a, b, c) __builtin_amdgcn_mfma_f32_16x16x32_bf16(a, b, c, 0, 0, 0)

// T4 primitives: counted vmcnt (never drain in-loop) + raw barrier + sched fence
#define VMCNT12() asm volatile("s_waitcnt vmcnt(12)" ::: "memory")
#define VMCNT0()  asm volatile("s_waitcnt vmcnt(0)" ::: "memory")
#define SFENCE()  __builtin_amdgcn_sched_barrier(0)
#define BAR()     __builtin_amdgcn_s_barrier()

static constexpr int M_TOT = 8192;   // B*S
static constexpr int DIN = 4096;
static constexpr int DOUT = 4096;
static constexpr int RNK = 64;

__device__ inline unsigned short f2bf(float f) {
    union { float f; unsigned u; } v; v.f = f;
    unsigned r = v.u + 0x7FFFu + ((v.u >> 16) & 1u);   // round-to-nearest-even
    return (unsigned short)(r >> 16);
}

// async global->LDS, 16 B per lane; LDS dest = wave-uniform base + lane*16
__device__ inline void gload_lds16(const float* g, char* lds_base) {
    __builtin_amdgcn_global_load_lds(
        (const __attribute__((address_space(1))) void*)g,
        (__attribute__((address_space(3))) void*)lds_base, 16, 0, 0);
}

// ---------------------------------------------------------------------------
// Fragment-major layout: block (tile,slice) holds the 64 lanes' bf16x8
// contiguously; every wave fragment load = one coalesced 1 KB instruction.
// ---------------------------------------------------------------------------
__global__ __launch_bounds__(256) void k_prep(const float* __restrict__ A,
                                              const float* __restrict__ B,
                                              unsigned short* __restrict__ Afrag,
                                              unsigned short* __restrict__ Atfrag,
                                              unsigned short* __restrict__ Bfrag) {
    int i = blockIdx.x * 256 + threadIdx.x;          // 0 .. 262143
    unsigned short ab = f2bf(A[i]);
    int n = i >> 12, k = i & 4095;                   // A[n][k]
    Afrag[(((k >> 5) << 2) + (n >> 4)) * 512 +
          ((((k >> 3) & 3) << 4) + (n & 15)) * 8 + (k & 7)] = ab;
    Atfrag[(((k >> 4) << 1) + (n >> 5)) * 512 +
           ((((n >> 3) & 3) << 4) + (k & 15)) * 8 + (n & 7)] = ab;
    unsigned short bb = f2bf(B[i]);
    int o = i >> 6, r = i & 63;
    Bfrag[(((o >> 4) << 1) + (r >> 5)) * 512 +
          ((((r >> 3) & 3) << 4) + (o & 15)) * 8 + (r & 7)] = bb;
}

// ---------------------------------------------------------------------------
// kAB: r14 bodies, but the chunk loop uses the T4 schedule:
//   vmcnt(12)  [batch c landed; batch c+1 STAYS IN FLIGHT]
//   s_barrier  [raw — no drain]
//   COMPUTE(c) [LDS + regs only]
//   s_barrier  [raw — read-done]
//   issue batch c+2  (4 global_load_lds + 8 frag reg-loads = 12 VMEM ops)
// No __syncthreads in the loop => no vmcnt(0) drains => loads stream
// continuously across barriers.
//   even blocks (1024): k1 role — 512 m-tiles x 2 K-halves, 8 chunks
//   odd  blocks (1024): k2 role — 256 o-tiles x 4 i-parts, 4 chunks
// ---------------------------------------------------------------------------
__global__ __launch_bounds__(256) void kAB(const float* __restrict__ x,
                                           const unsigned short* __restrict__ Afrag,
                                           float* __restrict__ pxa,
                                           const float* __restrict__ bw,
                                           const unsigned short* __restrict__ Bfrag,
                                           const unsigned short* __restrict__ Atfrag,
                                           float* __restrict__ pn) {
    __shared__ __align__(16) char smem[33024];
    char* buf0 = smem;
    char* buf1 = smem + 16384;
    int tid = threadIdx.x;
    int wid = tid >> 6, lane = tid & 63;
    int row = lane & 15, kq = lane >> 4;
    int lane8 = lane * 8;
    int swzr = (row & 7) << 4;
    int sub = blockIdx.x >> 1;

    if ((blockIdx.x & 1) == 0) {
        // ---------------- role 1: xa GEMM ----------------
        float (*red)[1024] = (float (*)[1024])smem;  // aliases buf0 after loop
        int mt = sub & 511, kpart = sub >> 9;
        int m0 = mt * 16;
        const float* xbase = x + (size_t)m0 * DIN + kpart * 2048;

        f32x4 acc0 = {0.f, 0.f, 0.f, 0.f};
        f32x4 acc1 = acc0, acc2 = acc0, acc3 = acc0;
        bf16x8 setA[8], setB[8];

        auto STAGE = [&](char* buf, int c) {
            #pragma unroll
            for (int j = 0; j < 4; ++j) {
                int r = wid * 4 + j;
                int srcb = (lane * 16) ^ ((r & 7) << 4);
                const float* g = xbase + (size_t)r * DIN + c * 256 + (srcb >> 2);
                gload_lds16(g, buf + r * 1024);
            }
        };
        auto AFRAG = [&](bf16x8* set, int c) {
            #pragma unroll
            for (int s = 0; s < 2; ++s) {
                int ks = kpart * 64 + c * 8 + wid * 2 + s;
                const unsigned short* ap = Afrag + (size_t)ks * 2048 + lane8;
                set[s * 4 + 0] = *(const bf16x8*)(ap);
                set[s * 4 + 1] = *(const bf16x8*)(ap + 512);
                set[s * 4 + 2] = *(const bf16x8*)(ap + 1024);
                set[s * 4 + 3] = *(const bf16x8*)(ap + 1536);
            }
        };
        auto COMPUTE = [&](const char* buf, const bf16x8* set) {
            #pragma unroll
            for (int s = 0; s < 2; ++s) {
                int kbyte = wid * 256 + s * 128 + kq * 32;
                f32x4 xlo = *(const f32x4*)(buf + row * 1024 + ((kbyte) ^ swzr));
                f32x4 xhi = *(const f32x4*)(buf + row * 1024 + ((kbyte + 16) ^ swzr));
                bf16x8 af;
                #pragma unroll
                for (int j = 0; j < 4; ++j) {
                    af[j] = (__bf16)xlo[j];
                    af[j + 4] = (__bf16)xhi[j];
                }
                acc0 = MFMA16(af, set[s * 4 + 0], acc0);
                acc1 = MFMA16(af, set[s * 4 + 1], acc1);
                acc2 = MFMA16(af, set[s * 4 + 2], acc2);
                acc3 = MFMA16(af, set[s * 4 + 3], acc3);
            }
        };

        STAGE(buf0, 0); AFRAG(setA, 0); SFENCE();
        STAGE(buf1, 1); AFRAG(setB, 1); SFENCE();
        #pragma unroll
        for (int c = 0; c < 6; c += 2) {
            VMCNT12(); BAR(); SFENCE();
            COMPUTE(buf0, setA);                      // chunk c
            SFENCE(); BAR();
            STAGE(buf0, c + 2); AFRAG(setA, c + 2); SFENCE();
            VMCNT12(); BAR(); SFENCE();
            COMPUTE(buf1, setB);                      // chunk c+1
            SFENCE(); BAR();
            STAGE(buf1, c + 3); AFRAG(setB, c + 3); SFENCE();
        }
        VMCNT12(); BAR(); SFENCE();
        COMPUTE(buf0, setA);                          // chunk 6
        SFENCE(); BAR();
        VMCNT0(); BAR(); SFENCE();
        COMPUTE(buf1, setB);                          // chunk 7

        int mb = kq * 4;                              // C: row=(lane>>4)*4+reg
        #pragma unroll
        for (int rg = 0; rg < 4; ++rg) {
            red[wid][(mb + rg) * 64 + row]      = acc0[rg];
            red[wid][(mb + rg) * 64 + 16 + row] = acc1[rg];
            red[wid][(mb + rg) * 64 + 32 + row] = acc2[rg];
            red[wid][(mb + rg) * 64 + 48 + row] = acc3[rg];
        }
        __syncthreads();
        #pragma unroll
        for (int e = tid; e < 1024; e += 256) {
            float s = red[0][e] + red[1][e] + red[2][e] + red[3][e];
            pxa[(size_t)kpart * M_TOT * RNK + (size_t)(m0 + (e >> 6)) * RNK + (e & 63)] = s;
        }
    } else {
        // ---------------- role 2: DoRA norm partials ----------------
        float (*part)[16] = (float (*)[16])(smem + 32768);
        int ot = sub & 255, ipart = sub >> 8;
        int o0 = ot * 16;
        const float* bwbase = bw + (size_t)o0 * DIN + ipart * 1024;

        bf16x8 b0 = *(const bf16x8*)(Bfrag + (size_t)(ot * 2) * 512 + lane8);
        bf16x8 b1 = *(const bf16x8*)(Bfrag + (size_t)(ot * 2 + 1) * 512 + lane8);

        f32x4 nacc = {0.f, 0.f, 0.f, 0.f};
        bf16x8 setA[8], setB[8];

        auto STAGE = [&](char* buf, int c) {
            #pragma unroll
            for (int j = 0; j < 4; ++j) {
                int r = wid * 4 + j;
                int srcb = (lane * 16) ^ ((r & 7) << 4);
                const float* g = bwbase + (size_t)r * DIN + c * 256 + (srcb >> 2);
                gload_lds16(g, buf + r * 1024);
            }
        };
        auto ATFRAG = [&](bf16x8* set, int c) {
            #pragma unroll
            for (int g = 0; g < 4; ++g) {
                int it = ipart * 64 + c * 16 + wid * 4 + g;
                const unsigned short* atp = Atfrag + (size_t)it * 1024 + lane8;
                set[g * 2]     = *(const bf16x8*)(atp);
                set[g * 2 + 1] = *(const bf16x8*)(atp + 512);
            }
        };
        auto COMPUTE = [&](const char* buf, const bf16x8* set) {
            #pragma unroll
            for (int g = 0; g < 4; ++g) {
                f32x4 d = {0.f, 0.f, 0.f, 0.f};
                d = MFMA16(set[g * 2], b0, d);       // delta[o=o0+row][i=..+kq*4+rg]
                d = MFMA16(set[g * 2 + 1], b1, d);
                int ibyte = wid * 256 + g * 64 + kq * 16;
                f32x4 wv = *(const f32x4*)(buf + row * 1024 + (ibyte ^ swzr));
                #pragma unroll
                for (int rg = 0; rg < 4; ++rg) {
                    float w = wv[rg] + 2.0f * d[rg];
                    nacc[rg] += w * w;
                }
            }
        };

        STAGE(buf0, 0); ATFRAG(setA, 0); SFENCE();
        STAGE(buf1, 1); ATFRAG(setB, 1); SFENCE();
        VMCNT12(); BAR(); SFENCE();
        COMPUTE(buf0, setA);                          // chunk 0
        SFENCE(); BAR();
        STAGE(buf0, 2); ATFRAG(setA, 2); SFENCE();
        VMCNT12(); BAR(); SFENCE();
        COMPUTE(buf1, setB);                          // chunk 1
        SFENCE(); BAR();
        STAGE(buf1, 3); ATFRAG(setB, 3); SFENCE();
        VMCNT12(); BAR(); SFENCE();
        COMPUTE(buf0, setA);                          // chunk 2
        SFENCE(); BAR();
        VMCNT0(); BAR(); SFENCE();
        COMPUTE(buf1, setB);                          // chunk 3

        float ns = nacc[0] + nacc[1] + nacc[2] + nacc[3];
        ns += __shfl_xor(ns, 16, 64);
        ns += __shfl_xor(ns, 32, 64);
        if (kq == 0) part[wid][row] = ns;
        __syncthreads();
        if (tid < 16)
            pn[ipart * DOUT + o0 + tid] =
                part[0][tid] + part[1][tid] + part[2][tid] + part[3][tid];
    }
}

// ---------------------------------------------------------------------------
// kfin: blocks 0..511: xa frag-major bf16 <- sum of 2 pxa planes;
//       blocks 512..527: mscale[o] = mag[o]/(sqrt(sum of 4 pn planes)+eps)
// ---------------------------------------------------------------------------
__global__ __launch_bounds__(256) void kfin(const float* __restrict__ pxa,
                                            unsigned short* __restrict__ xafrag,
                                            const float* __restrict__ pn,
                                            const float* __restrict__ mag,
                                            float* __restrict__ mscale) {
    int tid = threadIdx.x;
    if (blockIdx.x < 512) {
        int mt = blockIdx.x;
        int e0 = tid * 4;
        size_t o = (size_t)(mt * 16 + (e0 >> 6)) * RNK + (e0 & 63);
        f32x4 s0 = *(const f32x4*)(pxa + o);
        f32x4 s1 = *(const f32x4*)(pxa + (size_t)M_TOT * RNK + o);
        int ml = e0 >> 6, r0 = e0 & 63;
        ushort4 h;
        h.x = f2bf(s0[0] + s1[0]);
        h.y = f2bf(s0[1] + s1[1]);
        h.z = f2bf(s0[2] + s1[2]);
        h.w = f2bf(s0[3] + s1[3]);
        *(ushort4*)&xafrag[((size_t)(mt * 2 + (r0 >> 5))) * 512 +
                           ((((r0 >> 3) & 3) << 4) + ml) * 8 + (r0 & 7)] = h;
    } else {
        int o = (int)(blockIdx.x - 512) * 256 + tid;
        float n2 = pn[o] + pn[DOUT + o] + pn[2 * DOUT + o] + pn[3 * DOUT + o];
        mscale[o] = mag[o] / (sqrtf(n2) + 1e-8f);
    }
}

// ---------------------------------------------------------------------------
// kB: out = (base_output + 2 * xa @ lora_B^T) * mscale   (proven r7/r9 form)
// ---------------------------------------------------------------------------
__global__ __launch_bounds__(256) void kB(const float* __restrict__ base,
                                          const unsigned short* __restrict__ xafrag,
                                          const unsigned short* __restrict__ Bfrag,
                                          const float* __restrict__ mscale,
                                          float* __restrict__ out) {
    __shared__ float dls[32][260];                   // 33.3 KB, +4 pad
    int tid = threadIdx.x;
    int wid = tid >> 6, lane = tid & 63;
    int row = lane & 15, kq = lane >> 4;
    int m0 = blockIdx.x * 32;
    int n0 = blockIdx.y * 256;
    int col = n0 + lane * 4;
    int lane8 = lane * 8;

    f32x4 bpre[2][4];
    #pragma unroll
    for (int h = 0; h < 2; ++h)
        #pragma unroll
        for (int r = 0; r < 4; ++r)
            bpre[h][r] = __builtin_nontemporal_load(
                (const f32x4*)(base + (size_t)(m0 + h * 16 + wid * 4 + r) * DOUT + col));
    f32x4 msv = *(const f32x4*)(mscale + col);

    bf16x8 xb0[2], xb1[2];
    #pragma unroll
    for (int h = 0; h < 2; ++h) {
        size_t mt = (size_t)(blockIdx.x * 2 + h);
        xb0[h] = *(const bf16x8*)(xafrag + (mt * 2) * 512 + lane8);
        xb1[h] = *(const bf16x8*)(xafrag + (mt * 2 + 1) * 512 + lane8);
    }

    #pragma unroll
    for (int nt = 0; nt < 4; ++nt) {
        size_t ntg = (size_t)((n0 + wid * 64 + nt * 16) >> 4);
        bf16x8 a0 = *(const bf16x8*)(Bfrag + (ntg * 2) * 512 + lane8);
        bf16x8 a1 = *(const bf16x8*)(Bfrag + (ntg * 2 + 1) * 512 + lane8);
        #pragma unroll
        for (int h = 0; h < 2; ++h) {
            f32x4 acc = {0.f, 0.f, 0.f, 0.f};
            acc = MFMA16(a0, xb0[h], acc);           // lane: delta[m=row][nloc=kq*4+rg]
            acc = MFMA16(a1, xb1[h], acc);
            *(f32x4*)&dls[h * 16 + row][wid * 64 + nt * 16 + kq * 4] = acc;
        }
    }
    __syncthreads();

    #pragma unroll
    for (int h = 0; h < 2; ++h)
        #pragma unroll
        for (int r = 0; r < 4; ++r) {
            int m = h * 16 + wid * 4 + r;
            f32x4 d = *(const f32x4*)&dls[m][lane * 4];
            size_t gidx = (size_t)(m0 + m) * DOUT + col;
            f32x4 o;
            #pragma unroll
            for (int j = 0; j < 4; ++j) o[j] = (bpre[h][r][j] + 2.0f * d[j]) * msv[j];
            __builtin_nontemporal_store(o, (f32x4*)(out + gidx));
        }
}

extern "C" void kernel_launch(void* const* d_in, const int* in_sizes, int n_in,
                              void* d_out, int out_size, void* d_ws, size_t ws_size,
                              hipStream_t stream) {
    const float* x    = (const float*)d_in[0];   // [2,4096,4096]
    const float* base = (const float*)d_in[1];   // [2,4096,4096]
    const float* bw   = (const float*)d_in[2];   // [4096,4096]
    const float* lA   = (const float*)d_in[3];   // [64,4096]
    const float* lB   = (const float*)d_in[4];   // [4096,64]
    const float* mag  = (const float*)d_in[5];   // [4096]
    float* out = (float*)d_out;

    char* ws = (char*)d_ws;
    unsigned short* Afrag  = (unsigned short*)(ws);                  // 512 KB
    unsigned short* Atfrag = (unsigned short*)(ws + (512u << 10));   // 512 KB
    unsigned short* Bfrag  = (unsigned short*)(ws + (1024u << 10));  // 512 KB
    unsigned short* xafrag = (unsigned short*)(ws + (1536u << 10));  // 1 MB
    float*          pxa    = (float*)(ws + (2560u << 10));           // 4 MB
    float*          pn     = (float*)(ws + (6656u << 10));           // 64 KB
    float*          msc    = (float*)(ws + (6720u << 10));           // 16 KB

    hipLaunchKernelGGL(k_prep, dim3(1024), dim3(256), 0, stream, lA, lB, Afrag, Atfrag, Bfrag);
    hipLaunchKernelGGL(kAB, dim3(2048), dim3(256), 0, stream,
                       x, Afrag, pxa, bw, Bfrag, Atfrag, pn);
    hipLaunchKernelGGL(kfin, dim3(528), dim3(256), 0, stream, pxa, xafrag, pn, mag, msc);
    hipLaunchKernelGGL(kB, dim3(M_TOT / 32, DOUT / 256), dim3(256), 0, stream,
                       base, xafrag, Bfrag, msc, out);
}